// Round 16
// baseline (1700.336 us; speedup 1.0000x reference)
//
#include <hip/hip_runtime.h>
#include <math.h>

// Problem constants
#define Bsz   4
#define Tsz   4096
#define Csz   1024
#define Hn    16
#define DHn   64
#define NTOT  (Bsz * Tsz)      // 16384 rows of x
#define M3    (3 * Csz)        // 3072
#define Fn    2049             // T/2 + 1
#define BHn   (Bsz * Hn)       // 64
#define HALFN 8192             // 2 batches of columns

typedef __bf16 bf16x8 __attribute__((ext_vector_type(8)));
typedef __bf16 bf16x4 __attribute__((ext_vector_type(4)));
typedef float  f32x4  __attribute__((ext_vector_type(4)));

#define VMCNT(n) asm volatile("s_waitcnt vmcnt(" #n ")" ::: "memory")

// ---------------------------------------------------------------------------
// async global->LDS, 16B per lane. gptr per-lane; lptr wave-uniform
// (HW writes lptr + lane*16).
// ---------------------------------------------------------------------------
__device__ __forceinline__ void gload_lds16(const void* g, void* l) {
  __builtin_amdgcn_global_load_lds(
      (const __attribute__((address_space(1))) void*)g,
      (__attribute__((address_space(3))) void*)l, 16, 0, 0);
}

// ---------------------------------------------------------------------------
// f32 -> (hi, lo) bf16 split, 4 elems/thread. hi = RNE(v), lo = RNE(v - hi).
// ---------------------------------------------------------------------------
__global__ __launch_bounds__(256)
void cvt_hilo_kernel(const float4* __restrict__ in, bf16x4* __restrict__ hi,
                     bf16x4* __restrict__ lo, int n4) {
  int i = blockIdx.x * blockDim.x + threadIdx.x;
  if (i >= n4) return;
  float4 v = in[i];
  bf16x4 h, l;
  h[0] = (__bf16)v.x; h[1] = (__bf16)v.y; h[2] = (__bf16)v.z; h[3] = (__bf16)v.w;
  l[0] = (__bf16)(v.x - (float)h[0]);
  l[1] = (__bf16)(v.y - (float)h[1]);
  l[2] = (__bf16)(v.z - (float)h[2]);
  l[3] = (__bf16)(v.w - (float)h[3]);
  hi[i] = h;
  lo[i] = l;
}

// ---------------------------------------------------------------------------
// Transpose + hi/lo convert: src [1024][16384] f32 -> hi/lo [16384][1024] bf16.
// ---------------------------------------------------------------------------
__global__ __launch_bounds__(256)
void transpose_cvt_kernel(const float* __restrict__ src,
                          __bf16* __restrict__ hi, __bf16* __restrict__ lo) {
  __shared__ float tile[64][65];
  const int tid = threadIdx.x;
  const int n0 = blockIdx.x * 64;
  const int c0 = blockIdx.y * 64;
  const int col = tid & 63;
  const int row4 = tid >> 6;
#pragma unroll
  for (int i = 0; i < 16; ++i) {
    const int r = i * 4 + row4;
    tile[r][col] = src[(size_t)(c0 + r) * NTOT + n0 + col];
  }
  __syncthreads();
#pragma unroll
  for (int i = 0; i < 16; ++i) {
    const int n = i * 4 + row4;
    const float v = tile[col][n];
    const __bf16 h = (__bf16)v;
    const __bf16 l = (__bf16)(v - (float)h);
    hi[(size_t)(n0 + n) * Csz + c0 + col] = h;
    lo[(size_t)(n0 + n) * Csz + c0 + col] = l;
  }
}

// ===========================================================================
// gemm_8s: 4-slot single-tile ring, split-bf16 MFMA GEMM, 2 blocks/CU.
// 256x256 tile, 512 thr = 8 waves (2M x 4N), BK=32, K=1024.
// LDS 64KB: A0@0(16K), B0@16K(16K), B1@32K(16K), A1@48K(16K).
// Schedule (3 phases/tile, merged p2):
//   p0: vmcnt(2); bar; read A0,B0; stage A1(t) [all t]; MFMA(mh0,nh0)
//   p1: vmcnt(2); bar; read B1;    stage A0,B0(t+1);    MFMA(mh0,nh1)
//   p2: vmcnt(4|0); bar; read A1;  stage B1(t+1);       MFMA(mh1,nh0);(mh1,nh1)
// Ledger: every slot overwrite issued >=1 barrier after its read phase, whose
// ds_reads complete pre-barrier (consumed by that phase's MFMA). Per-wave
// counted vmcnt = own subsequent issues (others covered by their vmcnt before
// the shared barrier). Prologue stages A0,B0,B1 of t=0 -> p0(0) vmcnt(2) ok.
// FLOP order identical to the proven kernel -> bit-identical output.
// ===========================================================================
template<int COLMAP>
__global__ __launch_bounds__(512, 4)
void gemm_8s(const __bf16* __restrict__ Ahi, const __bf16* __restrict__ Alo,
             const __bf16* __restrict__ Bhi, const __bf16* __restrict__ Blo,
             float* __restrict__ C, int ldC, int nbase,
             const float* __restrict__ bias) {
  __shared__ __align__(16) char lds[65536];

  const int tid  = threadIdx.x;
  const int wid  = tid >> 6;
  const int lane = tid & 63;
  const int wm = wid >> 2, wn = wid & 3;

  int bx = blockIdx.x, by = blockIdx.y;
  {
    const int gx = gridDim.x, gy = gridDim.y;
    const int nwg = gx * gy;
    if ((nwg & 7) == 0) {
      const int flat  = by * gx + bx;
      const int chunk = nwg >> 3;
      const int nf    = (flat & 7) * chunk + (flat >> 3);
      if (COLMAP) { bx = nf / gy; by = nf % gy; }
      else        { bx = nf % gx; by = nf / gx; }
    }
  }
  const int m0 = by * 256;
  const int n0 = bx * 256;

  const int r16 = lane & 15;
  const int kc  = lane >> 4;

  const int aq = (wid & 3) + ((wid & 4) ? 4 : 0);
  const int bq = ((wid & 3) << 1) + (wid >> 2);
  const __bf16* gAh = Ahi + (size_t)(m0 + (wid & 3) * 16 + ((wid & 4) ? 128 : 0) + r16) * Csz + kc * 8;
  const __bf16* gAl = Alo + (size_t)(m0 + (wid & 3) * 16 + ((wid & 4) ? 128 : 0) + r16) * Csz + kc * 8;
  const __bf16* gBh = Bhi + (size_t)(n0 + (wid & 3) * 64 + (wid >> 2) * 16 + r16) * Csz + kc * 8;
  const __bf16* gBl = Blo + (size_t)(n0 + (wid & 3) * 64 + (wid >> 2) * 16 + r16) * Csz + kc * 8;

  auto stA = [&](int h, int ts, char* slot) {
    const size_t o = (size_t)h * 64 * Csz + ts * 32;
    gload_lds16(gAh + o, slot + aq * 1024);
    gload_lds16(gAl + o, slot + 8192 + aq * 1024);
  };
  auto stB = [&](int h, int ts, char* slot) {
    const size_t o = (size_t)h * 32 * Csz + ts * 32;
    gload_lds16(gBh + o, slot + bq * 1024);
    gload_lds16(gBl + o, slot + 8192 + bq * 1024);
  };

  f32x4 acc[8][4];
#pragma unroll
  for (int i = 0; i < 8; ++i)
#pragma unroll
    for (int j = 0; j < 4; ++j) acc[i][j] = (f32x4)(0.f);

  // prologue: A0(0), B0(0), B1(0); A1(0) staged in p0(0)
  stA(0, 0, lds);
  stB(0, 0, lds + 16384);
  stB(1, 0, lds + 32768);

#pragma unroll 1
  for (int t = 0; t < 32; ++t) {
    bf16x8 ah[4], al[4], bh[4], bl[4];

    // ---- phase 0: read A0(t), B0(t); stage A1(t); MFMA (mh0, nh0)
    VMCNT(2);
    __builtin_amdgcn_s_barrier();
#pragma unroll
    for (int f = 0; f < 4; ++f) {
      const int off = (wm * 4 + f) * 1024 + lane * 16;
      ah[f] = *(const bf16x8*)(lds + off);
      al[f] = *(const bf16x8*)(lds + 8192 + off);
    }
#pragma unroll
    for (int j = 0; j < 2; ++j) {
      const int off = ((wn << 1) + j) * 1024 + lane * 16;
      bh[j] = *(const bf16x8*)(lds + 16384 + off);
      bl[j] = *(const bf16x8*)(lds + 16384 + 8192 + off);
    }
    stA(1, t, lds + 49152);
    __builtin_amdgcn_s_setprio(1);
#pragma unroll
    for (int f = 0; f < 4; ++f)
#pragma unroll
      for (int j = 0; j < 2; ++j) {
        f32x4 a_ = acc[f][j];
        a_ = __builtin_amdgcn_mfma_f32_16x16x32_bf16(ah[f], bh[j], a_, 0, 0, 0);
        a_ = __builtin_amdgcn_mfma_f32_16x16x32_bf16(ah[f], bl[j], a_, 0, 0, 0);
        a_ = __builtin_amdgcn_mfma_f32_16x16x32_bf16(al[f], bh[j], a_, 0, 0, 0);
        acc[f][j] = a_;
      }
    __builtin_amdgcn_s_setprio(0);

    // ---- phase 1: read B1(t); stage A0,B0(t+1); MFMA (mh0, nh1)
    VMCNT(2);
    __builtin_amdgcn_s_barrier();
#pragma unroll
    for (int j = 0; j < 2; ++j) {
      const int off = ((wn << 1) + j) * 1024 + lane * 16;
      bh[2 + j] = *(const bf16x8*)(lds + 32768 + off);
      bl[2 + j] = *(const bf16x8*)(lds + 32768 + 8192 + off);
    }
    if (t < 31) { stA(0, t + 1, lds); stB(0, t + 1, lds + 16384); }
    __builtin_amdgcn_s_setprio(1);
#pragma unroll
    for (int f = 0; f < 4; ++f)
#pragma unroll
      for (int j = 0; j < 2; ++j) {
        f32x4 a_ = acc[f][2 + j];
        a_ = __builtin_amdgcn_mfma_f32_16x16x32_bf16(ah[f], bh[2 + j], a_, 0, 0, 0);
        a_ = __builtin_amdgcn_mfma_f32_16x16x32_bf16(ah[f], bl[2 + j], a_, 0, 0, 0);
        a_ = __builtin_amdgcn_mfma_f32_16x16x32_bf16(al[f], bh[2 + j], a_, 0, 0, 0);
        acc[f][2 + j] = a_;
      }
    __builtin_amdgcn_s_setprio(0);

    // ---- phase 2 (merged): read A1(t); stage B1(t+1); MFMA (mh1, nh0+nh1)
    if (t < 31) { VMCNT(4); } else { VMCNT(0); }
    __builtin_amdgcn_s_barrier();
#pragma unroll
    for (int f = 0; f < 4; ++f) {
      const int off = (wm * 4 + f) * 1024 + lane * 16;
      ah[f] = *(const bf16x8*)(lds + 49152 + off);
      al[f] = *(const bf16x8*)(lds + 49152 + 8192 + off);
    }
    if (t < 31) stB(1, t + 1, lds + 32768);
    __builtin_amdgcn_s_setprio(1);
#pragma unroll
    for (int f = 0; f < 4; ++f)
#pragma unroll
      for (int j = 0; j < 2; ++j) {
        f32x4 a_ = acc[4 + f][j];
        a_ = __builtin_amdgcn_mfma_f32_16x16x32_bf16(ah[f], bh[j], a_, 0, 0, 0);
        a_ = __builtin_amdgcn_mfma_f32_16x16x32_bf16(ah[f], bl[j], a_, 0, 0, 0);
        a_ = __builtin_amdgcn_mfma_f32_16x16x32_bf16(al[f], bh[j], a_, 0, 0, 0);
        acc[4 + f][j] = a_;
      }
#pragma unroll
    for (int f = 0; f < 4; ++f)
#pragma unroll
      for (int j = 0; j < 2; ++j) {
        f32x4 a_ = acc[4 + f][2 + j];
        a_ = __builtin_amdgcn_mfma_f32_16x16x32_bf16(ah[f], bh[2 + j], a_, 0, 0, 0);
        a_ = __builtin_amdgcn_mfma_f32_16x16x32_bf16(ah[f], bl[2 + j], a_, 0, 0, 0);
        a_ = __builtin_amdgcn_mfma_f32_16x16x32_bf16(al[f], bh[2 + j], a_, 0, 0, 0);
        acc[4 + f][2 + j] = a_;
      }
    __builtin_amdgcn_s_setprio(0);
  }

  const int cm = m0 + wm * 128 + (lane >> 4) * 4;
  const int cn = nbase + n0 + wn * 64 + (lane & 15);
  float bb[4];
#pragma unroll
  for (int g = 0; g < 4; ++g) bb[g] = bias ? bias[cn - nbase + g * 16] : 0.f;
#pragma unroll
  for (int fm = 0; fm < 8; ++fm)
#pragma unroll
    for (int r = 0; r < 4; ++r) {
      float* cp = C + (size_t)(cm + fm * 16 + r) * ldC + cn;
#pragma unroll
      for (int g = 0; g < 4; ++g) cp[g * 16] = acc[fm][g][r] + bb[g];
    }
}

// ===========================================================================
// gemm_8s4: 4-slot ring at BM=128 (v-GEMM). LDS 48KB -> 2 blocks/CU.
// Slots: A0@0(8K), B0@8K(16K), B1@24K(16K), A1@40K(8K).
// Per-wave issues: A=1, B=2 -> vmcnt p0=2, p1=1, p2=3 (t=31: 0).
// ===========================================================================
template<int COLMAP>
__global__ __launch_bounds__(512, 4)
void gemm_8s4(const __bf16* __restrict__ Ahi, const __bf16* __restrict__ Alo,
              const __bf16* __restrict__ Bhi, const __bf16* __restrict__ Blo,
              float* __restrict__ C, int ldC, int nbase,
              const float* __restrict__ bias) {
  __shared__ __align__(16) char lds[49152];

  const int tid  = threadIdx.x;
  const int wid  = tid >> 6;
  const int lane = tid & 63;
  const int wm = wid >> 2, wn = wid & 3;

  int bx = blockIdx.x, by = blockIdx.y;
  {
    const int gx = gridDim.x, gy = gridDim.y;
    const int nwg = gx * gy;
    if ((nwg & 7) == 0) {
      const int flat  = by * gx + bx;
      const int chunk = nwg >> 3;
      const int nf    = (flat & 7) * chunk + (flat >> 3);
      if (COLMAP) { bx = nf / gy; by = nf % gy; }
      else        { bx = nf % gx; by = nf / gx; }
    }
  }
  const int m0 = by * 128;
  const int n0 = bx * 256;

  const int r16 = lane & 15;
  const int kc  = lane >> 4;

  const int cw = wid & 3;
  const __bf16* gA = ((wid & 4) ? Alo : Ahi) +
      (size_t)(m0 + (cw >> 1) * 64 + (cw & 1) * 16 + r16) * Csz + kc * 8;
  const int adst = ((wid & 4) ? 4096 : 0) + cw * 1024;
  const int bq = ((wid & 3) << 1) + (wid >> 2);
  const __bf16* gBh = Bhi + (size_t)(n0 + (wid & 3) * 64 + (wid >> 2) * 16 + r16) * Csz + kc * 8;
  const __bf16* gBl = Blo + (size_t)(n0 + (wid & 3) * 64 + (wid >> 2) * 16 + r16) * Csz + kc * 8;

  auto stA = [&](int h, int ts, char* slot) {
    gload_lds16(gA + (size_t)h * 32 * Csz + ts * 32, slot + adst);
  };
  auto stB = [&](int h, int ts, char* slot) {
    const size_t o = (size_t)h * 32 * Csz + ts * 32;
    gload_lds16(gBh + o, slot + bq * 1024);
    gload_lds16(gBl + o, slot + 8192 + bq * 1024);
  };

  f32x4 acc[4][4];
#pragma unroll
  for (int i = 0; i < 4; ++i)
#pragma unroll
    for (int j = 0; j < 4; ++j) acc[i][j] = (f32x4)(0.f);

  stA(0, 0, lds);
  stB(0, 0, lds + 8192);
  stB(1, 0, lds + 24576);

#pragma unroll 1
  for (int t = 0; t < 32; ++t) {
    bf16x8 ah[2], al[2], bh[4], bl[4];

    // ---- phase 0: read A0, B0; stage A1(t); MFMA (mh0, nh0)
    VMCNT(2);
    __builtin_amdgcn_s_barrier();
#pragma unroll
    for (int f = 0; f < 2; ++f) {
      const int off = (wm * 2 + f) * 1024 + lane * 16;
      ah[f] = *(const bf16x8*)(lds + off);
      al[f] = *(const bf16x8*)(lds + 4096 + off);
    }
#pragma unroll
    for (int j = 0; j < 2; ++j) {
      const int off = ((wn << 1) + j) * 1024 + lane * 16;
      bh[j] = *(const bf16x8*)(lds + 8192 + off);
      bl[j] = *(const bf16x8*)(lds + 8192 + 8192 + off);
    }
    stA(1, t, lds + 40960);
    __builtin_amdgcn_s_setprio(1);
#pragma unroll
    for (int f = 0; f < 2; ++f)
#pragma unroll
      for (int j = 0; j < 2; ++j) {
        f32x4 a_ = acc[f][j];
        a_ = __builtin_amdgcn_mfma_f32_16x16x32_bf16(ah[f], bh[j], a_, 0, 0, 0);
        a_ = __builtin_amdgcn_mfma_f32_16x16x32_bf16(ah[f], bl[j], a_, 0, 0, 0);
        a_ = __builtin_amdgcn_mfma_f32_16x16x32_bf16(al[f], bh[j], a_, 0, 0, 0);
        acc[f][j] = a_;
      }
    __builtin_amdgcn_s_setprio(0);

    // ---- phase 1: read B1; stage A0,B0(t+1); MFMA (mh0, nh1)
    VMCNT(1);
    __builtin_amdgcn_s_barrier();
#pragma unroll
    for (int j = 0; j < 2; ++j) {
      const int off = ((wn << 1) + j) * 1024 + lane * 16;
      bh[2 + j] = *(const bf16x8*)(lds + 24576 + off);
      bl[2 + j] = *(const bf16x8*)(lds + 24576 + 8192 + off);
    }
    if (t < 31) { stA(0, t + 1, lds); stB(0, t + 1, lds + 8192); }
    __builtin_amdgcn_s_setprio(1);
#pragma unroll
    for (int f = 0; f < 2; ++f)
#pragma unroll
      for (int j = 0; j < 2; ++j) {
        f32x4 a_ = acc[f][2 + j];
        a_ = __builtin_amdgcn_mfma_f32_16x16x32_bf16(ah[f], bh[2 + j], a_, 0, 0, 0);
        a_ = __builtin_amdgcn_mfma_f32_16x16x32_bf16(ah[f], bl[2 + j], a_, 0, 0, 0);
        a_ = __builtin_amdgcn_mfma_f32_16x16x32_bf16(al[f], bh[2 + j], a_, 0, 0, 0);
        acc[f][2 + j] = a_;
      }
    __builtin_amdgcn_s_setprio(0);

    // ---- phase 2 (merged): read A1; stage B1(t+1); MFMA (mh1, nh0+nh1)
    if (t < 31) { VMCNT(3); } else { VMCNT(0); }
    __builtin_amdgcn_s_barrier();
#pragma unroll
    for (int f = 0; f < 2; ++f) {
      const int off = (wm * 2 + f) * 1024 + lane * 16;
      ah[f] = *(const bf16x8*)(lds + 40960 + off);
      al[f] = *(const bf16x8*)(lds + 40960 + 4096 + off);
    }
    if (t < 31) stB(1, t + 1, lds + 24576);
    __builtin_amdgcn_s_setprio(1);
#pragma unroll
    for (int f = 0; f < 2; ++f)
#pragma unroll
      for (int j = 0; j < 2; ++j) {
        f32x4 a_ = acc[2 + f][j];
        a_ = __builtin_amdgcn_mfma_f32_16x16x32_bf16(ah[f], bh[j], a_, 0, 0, 0);
        a_ = __builtin_amdgcn_mfma_f32_16x16x32_bf16(ah[f], bl[j], a_, 0, 0, 0);
        a_ = __builtin_amdgcn_mfma_f32_16x16x32_bf16(al[f], bh[j], a_, 0, 0, 0);
        acc[2 + f][j] = a_;
      }
#pragma unroll
    for (int f = 0; f < 2; ++f)
#pragma unroll
      for (int j = 0; j < 2; ++j) {
        f32x4 a_ = acc[2 + f][2 + j];
        a_ = __builtin_amdgcn_mfma_f32_16x16x32_bf16(ah[f], bh[2 + j], a_, 0, 0, 0);
        a_ = __builtin_amdgcn_mfma_f32_16x16x32_bf16(ah[f], bl[2 + j], a_, 0, 0, 0);
        a_ = __builtin_amdgcn_mfma_f32_16x16x32_bf16(al[f], bh[2 + j], a_, 0, 0, 0);
        acc[2 + f][2 + j] = a_;
      }
    __builtin_amdgcn_s_setprio(0);
  }

  const int cm = m0 + wm * 64 + (lane >> 4) * 4;
  const int cn = nbase + n0 + wn * 64 + (lane & 15);
  float bb[4];
#pragma unroll
  for (int g = 0; g < 4; ++g) bb[g] = bias ? bias[cn - nbase + g * 16] : 0.f;
#pragma unroll
  for (int fm = 0; fm < 4; ++fm)
#pragma unroll
    for (int r = 0; r < 4; ++r) {
      float* cp = C + (size_t)(cm + fm * 16 + r) * ldC + cn;
#pragma unroll
      for (int g = 0; g < 4; ++g) cp[g * 16] = acc[fm][g][r] + bb[g];
    }
}

// ===========================================================================
// Radix-4 Stockham FFT, 4096 = 4^6, 6 stages, LDS twiddle table.
// PAIRED variant (round-13 proven): 512 threads, thread u handles
// butterflies {2u, 2u+1}; float4 LDS reads/writes; shared twiddles per pair
// for stages >=1. Bit-identical to the unpaired version.
// ===========================================================================
__device__ __forceinline__ void build_twiddle512(float2* tw, int tid) {
  const float k = 6.28318530717958647692f / 4096.0f;
#pragma unroll
  for (int i = 0; i < 2; ++i) {
    const int e = tid + i * 512;
    float sn, cs;
    __sincosf(k * (float)e, &sn, &cs);
    tw[e] = make_float2(cs, sn);
  }
}

__device__ __forceinline__ float2 cmul(float2 a, float2 b) {
  return make_float2(a.x * b.x - a.y * b.y, a.x * b.y + a.y * b.x);
}

__device__ __forceinline__ void fft4096_r4p(float2* X, float2* Y,
                                            const float2* __restrict__ tw,
                                            int tid, float sign) {
  float2* src = X;
  float2* dst = Y;
#pragma unroll 1
  for (int stage = 0; stage < 6; ++stage) {
    const int s = 1 << (2 * stage);
    __syncthreads();
    const int i0 = tid << 1;                    // 0,2,...,1022
    float4 A0 = *(const float4*)(src + i0);
    float4 A1 = *(const float4*)(src + i0 + 1024);
    float4 A2 = *(const float4*)(src + i0 + 2048);
    float4 A3 = *(const float4*)(src + i0 + 3072);
    float2 y[2][4];
#pragma unroll
    for (int e = 0; e < 2; ++e) {
      const float2 a0 = e ? make_float2(A0.z, A0.w) : make_float2(A0.x, A0.y);
      const float2 a1 = e ? make_float2(A1.z, A1.w) : make_float2(A1.x, A1.y);
      const float2 a2 = e ? make_float2(A2.z, A2.w) : make_float2(A2.x, A2.y);
      const float2 a3 = e ? make_float2(A3.z, A3.w) : make_float2(A3.x, A3.y);
      float2 b0 = make_float2(a0.x + a2.x, a0.y + a2.y);
      float2 b1 = make_float2(a0.x - a2.x, a0.y - a2.y);
      float2 b2 = make_float2(a1.x + a3.x, a1.y + a3.y);
      float2 b3 = make_float2(a1.x - a3.x, a1.y - a3.y);
      y[e][0] = make_float2(b0.x + b2.x, b0.y + b2.y);
      y[e][2] = make_float2(b0.x - b2.x, b0.y - b2.y);
      y[e][1] = make_float2(b1.x - sign * b3.y, b1.y + sign * b3.x);
      y[e][3] = make_float2(b1.x + sign * b3.y, b1.y - sign * b3.x);
    }
    if (stage == 0) {
#pragma unroll
      for (int e = 0; e < 2; ++e) {
        const int idx = i0 + e;
        float2 w1 = tw[idx];
        w1.y *= sign;
        float2 w2 = make_float2(w1.x * w1.x - w1.y * w1.y, 2.f * w1.x * w1.y);
        float2 w3 = cmul(w1, w2);
        float2 t1 = cmul(w1, y[e][1]);
        float2 t2 = cmul(w2, y[e][2]);
        float2 t3 = cmul(w3, y[e][3]);
        const int o = idx << 2;
        *(float4*)(dst + o)     = make_float4(y[e][0].x, y[e][0].y, t1.x, t1.y);
        *(float4*)(dst + o + 2) = make_float4(t2.x, t2.y, t3.x, t3.y);
      }
    } else {
      const int sp = i0 & ~(s - 1);
      float2 w1 = tw[sp];
      w1.y *= sign;
      float2 w2 = make_float2(w1.x * w1.x - w1.y * w1.y, 2.f * w1.x * w1.y);
      float2 w3 = cmul(w1, w2);
      const int o = i0 + 3 * sp;
      *(float4*)(dst + o) = make_float4(y[0][0].x, y[0][0].y, y[1][0].x, y[1][0].y);
      float2 p0 = cmul(w1, y[0][1]);
      float2 p1 = cmul(w1, y[1][1]);
      *(float4*)(dst + o + s) = make_float4(p0.x, p0.y, p1.x, p1.y);
      p0 = cmul(w2, y[0][2]);
      p1 = cmul(w2, y[1][2]);
      *(float4*)(dst + o + 2 * s) = make_float4(p0.x, p0.y, p1.x, p1.y);
      p0 = cmul(w3, y[0][3]);
      p1 = cmul(w3, y[1][3]);
      *(float4*)(dst + o + 3 * s) = make_float4(p0.x, p0.y, p1.x, p1.y);
    }
    float2* t = src; src = dst; dst = t;
  }
  __syncthreads();
}

// ---------------------------------------------------------------------------
// qk_cross (512 thr): z = q + i*k, FFT, Re(conj(Q)K) via packed extraction.
// ---------------------------------------------------------------------------
__global__ __launch_bounds__(512)
void qk_cross_kernel(const float* __restrict__ qkT, float* __restrict__ attn_raw,
                     int bhbase) {
  __shared__ float2 bufA[4096];
  __shared__ float2 bufB[4096];
  __shared__ float2 twid[1024];
  const int tid = threadIdx.x;
  const int blk = blockIdx.x;
  const int d = blk & 63;
  const int bh = bhbase + (blk >> 6);
  const int h = bh & 15;
  const int b = bh >> 4;

  build_twiddle512(twid, tid);

  const float4* qrow = (const float4*)(qkT + (size_t)(h * DHn + d) * NTOT + b * Tsz);
  const float4* krow = (const float4*)(qkT + (size_t)(Csz + h * DHn + d) * NTOT + b * Tsz);
#pragma unroll
  for (int i = 0; i < 2; ++i) {
    const int t4 = tid + (i << 9);           // < 1024
    float4 qv = qrow[t4];
    float4 kv = krow[t4];
    bufA[t4 * 4 + 0] = make_float2(qv.x, kv.x);
    bufA[t4 * 4 + 1] = make_float2(qv.y, kv.y);
    bufA[t4 * 4 + 2] = make_float2(qv.z, kv.z);
    bufA[t4 * 4 + 3] = make_float2(qv.w, kv.w);
  }

  fft4096_r4p(bufA, bufB, twid, tid, -1.0f);

  float* outp = attn_raw + (size_t)bh * Fn;
  for (int f = tid; f < Fn; f += 512) {
    float2 zf = bufA[f];
    float2 zn = bufA[(4096 - f) & 4095];
    float ar = zf.x + zn.x;
    float ai = zf.y - zn.y;
    float br = zf.x - zn.x;
    float bi = zf.y + zn.y;
    float val = 0.03125f * (ar * bi - ai * br);
    atomicAdd(&outp[f], val);
  }
}

// ---------------------------------------------------------------------------
__global__ __launch_bounds__(256)
void softmax_kernel(const float* __restrict__ raw, float* __restrict__ attn) {
  __shared__ float red[256];
  const int tid = threadIdx.x;
  const float* in = raw + (size_t)blockIdx.x * Fn;
  float* outp = attn + (size_t)blockIdx.x * Fn;

  float lmax = -3.4e38f;
  for (int f = tid; f < Fn; f += 256) lmax = fmaxf(lmax, in[f]);
  red[tid] = lmax;
  __syncthreads();
  for (int off = 128; off > 0; off >>= 1) {
    if (tid < off) red[tid] = fmaxf(red[tid], red[tid + off]);
    __syncthreads();
  }
  const float mx = red[0];
  __syncthreads();

  float lsum = 0.f;
  for (int f = tid; f < Fn; f += 256) lsum += __expf(in[f] - mx);
  red[tid] = lsum;
  __syncthreads();
  for (int off = 128; off > 0; off >>= 1) {
    if (tid < off) red[tid] += red[tid + off];
    __syncthreads();
  }
  const float inv = 1.0f / red[0];
  for (int f = tid; f < Fn; f += 256) outp[f] = __expf(in[f] - mx) * inv;
}

// ---------------------------------------------------------------------------
// v_filter (512 thr): z = v[d0]+i*v[d1]; FFT; real symmetric filter; IFFT.
// ---------------------------------------------------------------------------
__global__ __launch_bounds__(512)
void v_filter_kernel(const float* __restrict__ vT, float* __restrict__ vbarT,
                     const float* __restrict__ attn) {
  __shared__ float2 bufA[4096];
  __shared__ float2 bufB[4096];
  __shared__ float2 twid[1024];
  const int tid = threadIdx.x;
  const int blk = blockIdx.x;
  const int jp = blk & 31;
  const int bh = blk >> 5;
  const int h = bh & 15;
  const int b = bh >> 4;
  const int d0 = jp * 2;

  build_twiddle512(twid, tid);

  const float4* v0 = (const float4*)(vT + (size_t)(h * DHn + d0) * NTOT + b * Tsz);
  const float4* v1 = (const float4*)(vT + (size_t)(h * DHn + d0 + 1) * NTOT + b * Tsz);
#pragma unroll
  for (int i = 0; i < 2; ++i) {
    const int t4 = tid + (i << 9);
    float4 av = v0[t4];
    float4 bv = v1[t4];
    bufA[t4 * 4 + 0] = make_float2(av.x, bv.x);
    bufA[t4 * 4 + 1] = make_float2(av.y, bv.y);
    bufA[t4 * 4 + 2] = make_float2(av.z, bv.z);
    bufA[t4 * 4 + 3] = make_float2(av.w, bv.w);
  }

  fft4096_r4p(bufA, bufB, twid, tid, -1.0f);

  const float* a = attn + (size_t)bh * Fn;
  for (int f = tid; f < 4096; f += 512) {
    int fm = (f <= 2048) ? f : (4096 - f);
    float s = a[fm];
    float2 z = bufA[f];
    bufA[f] = make_float2(z.x * s, z.y * s);
  }

  fft4096_r4p(bufA, bufB, twid, tid, +1.0f);

  float* y0 = vbarT + (size_t)(h * DHn + d0) * NTOT + b * Tsz;
  float* y1 = y0 + NTOT;
  const float inv = 1.0f / 4096.0f;
  for (int t = tid; t < 4096; t += 512) {
    float2 z = bufA[t];
    y0[t] = z.x * inv;
    y1[t] = z.y * inv;
  }
}

__global__ void zero_kernel(float* __restrict__ p, int n) {
  int i = blockIdx.x * blockDim.x + threadIdx.x;
  if (i < n) p[i] = 0.f;
}

// ---------------------------------------------------------------------------
// Workspace layout (peak 185,598,464 B <= 202.9 MB proven by round 1):
//   [0,           67108864)   q rows of qkT; later vT; finally VThi/VTlo.
//   [67108864,   134217728)   k rows of qkT; later vbarT.
//   [134217728,  134742272)   attn_raw [64][2049] f32
//   [134742272,  135266816)   attn     [64][2049] f32
//   [135266816,  141558272)   Whi [3072][1024] bf16
//   [141558272,  147849728)   Wlo
//   [147849728,  164626944)   Xhi half [8192][1024] bf16 (2 halves, reused)
//   [164626944,  181404160)   Xlo half
//   [181404160,  183501312)   Wouthi [1024][1024] bf16
//   [183501312,  185598464)   Woutlo
// ---------------------------------------------------------------------------
extern "C" void kernel_launch(void* const* d_in, const int* in_sizes, int n_in,
                              void* d_out, int out_size, void* d_ws, size_t ws_size,
                              hipStream_t stream) {
  const float* x    = (const float*)d_in[0];   // [4,4096,1024]
  const float* Wqkv = (const float*)d_in[1];   // [3072,1024]
  const float* Wout = (const float*)d_in[2];   // [1024,1024]
  const float* bout = (const float*)d_in[3];   // [1024]
  float* out = (float*)d_out;                  // [16384,1024]

  char* ws = (char*)d_ws;
  float* qkT      = (float*)ws;
  float* vT       = (float*)ws;
  __bf16* VThi    = (__bf16*)ws;
  __bf16* VTlo    = (__bf16*)(ws + 33554432ull);
  float* vbarT    = (float*)(ws + 67108864ull);
  float* attn_raw = (float*)(ws + 134217728ull);
  float* attn     = (float*)(ws + 134742272ull);
  __bf16* Whi     = (__bf16*)(ws + 135266816ull);
  __bf16* Wlo     = (__bf16*)(ws + 141558272ull);
  __bf16* Xhi     = (__bf16*)(ws + 147849728ull);
  __bf16* Xlo     = (__bf16*)(ws + 164626944ull);
  __bf16* Wouthi  = (__bf16*)(ws + 181404160ull);
  __bf16* Woutlo  = (__bf16*)(ws + 183501312ull);

  const int nraw = BHn * Fn;
  zero_kernel<<<(nraw + 255) / 256, 256, 0, stream>>>(attn_raw, nraw);

  // Weights -> hi/lo
  cvt_hilo_kernel<<<3072, 256, 0, stream>>>((const float4*)Wqkv,
                                            (bf16x4*)Whi, (bf16x4*)Wlo, 786432);
  cvt_hilo_kernel<<<1024, 256, 0, stream>>>((const float4*)Wout,
                                            (bf16x4*)Wouthi, (bf16x4*)Woutlo, 262144);

  // Per 2-batch half: convert X, q/k GEMM (4-slot ring), qk cross, v GEMM
  for (int half = 0; half < 2; ++half) {
    cvt_hilo_kernel<<<8192, 256, 0, stream>>>(
        (const float4*)(x + (size_t)half * HALFN * Csz),
        (bf16x4*)Xhi, (bf16x4*)Xlo, 2097152);
    gemm_8s<1><<<dim3(32, 8), 512, 0, stream>>>(Whi, Wlo, Xhi, Xlo,
                                                qkT, NTOT, half * HALFN, nullptr);
    qk_cross_kernel<<<2048, 512, 0, stream>>>(qkT, attn_raw, half * 32);
    gemm_8s4<1><<<dim3(32, 8), 512, 0, stream>>>(Whi + 2048 * Csz, Wlo + 2048 * Csz,
                                                 Xhi, Xlo, vT, NTOT, half * HALFN,
                                                 nullptr);
  }

  softmax_kernel<<<BHn, 256, 0, stream>>>(attn_raw, attn);

  v_filter_kernel<<<2048, 512, 0, stream>>>(vT, vbarT, attn);

  transpose_cvt_kernel<<<dim3(NTOT / 64, Csz / 64), 256, 0, stream>>>(vbarT, VThi, VTlo);

  gemm_8s<0><<<dim3(4, 64), 512, 0, stream>>>(VThi, VTlo, Wouthi, Woutlo,
                                              out, Csz, 0, bout);
}

// Round 17
// 548.022 us; speedup vs baseline: 3.1027x; 3.1027x over previous
//
#include <hip/hip_runtime.h>
#include <math.h>

// Problem constants
#define Bsz   4
#define Tsz   4096
#define Csz   1024
#define Hn    16
#define DHn   64
#define NTOT  (Bsz * Tsz)      // 16384 rows of x
#define M3    (3 * Csz)        // 3072
#define Fn    2049             // T/2 + 1
#define BHn   (Bsz * Hn)       // 64
#define HALFN 8192             // 2 batches of columns

typedef __bf16 bf16x8 __attribute__((ext_vector_type(8)));
typedef __bf16 bf16x4 __attribute__((ext_vector_type(4)));
typedef float  f32x4  __attribute__((ext_vector_type(4)));

#define VMCNT(n) asm volatile("s_waitcnt vmcnt(" #n ")" ::: "memory")

// ---------------------------------------------------------------------------
// async global->LDS, 16B per lane. gptr per-lane; lptr wave-uniform
// (HW writes lptr + lane*16).
// ---------------------------------------------------------------------------
__device__ __forceinline__ void gload_lds16(const void* g, void* l) {
  __builtin_amdgcn_global_load_lds(
      (const __attribute__((address_space(1))) void*)g,
      (__attribute__((address_space(3))) void*)l, 16, 0, 0);
}

// ---------------------------------------------------------------------------
// f32 -> (hi, lo) bf16 split, 4 elems/thread. hi = RNE(v), lo = RNE(v - hi).
// ---------------------------------------------------------------------------
__global__ __launch_bounds__(256)
void cvt_hilo_kernel(const float4* __restrict__ in, bf16x4* __restrict__ hi,
                     bf16x4* __restrict__ lo, int n4) {
  int i = blockIdx.x * blockDim.x + threadIdx.x;
  if (i >= n4) return;
  float4 v = in[i];
  bf16x4 h, l;
  h[0] = (__bf16)v.x; h[1] = (__bf16)v.y; h[2] = (__bf16)v.z; h[3] = (__bf16)v.w;
  l[0] = (__bf16)(v.x - (float)h[0]);
  l[1] = (__bf16)(v.y - (float)h[1]);
  l[2] = (__bf16)(v.z - (float)h[2]);
  l[3] = (__bf16)(v.w - (float)h[3]);
  hi[i] = h;
  lo[i] = l;
}

// ---------------------------------------------------------------------------
// Transpose + hi/lo convert: src [1024][16384] f32 -> hi/lo [16384][1024] bf16.
// ---------------------------------------------------------------------------
__global__ __launch_bounds__(256)
void transpose_cvt_kernel(const float* __restrict__ src,
                          __bf16* __restrict__ hi, __bf16* __restrict__ lo) {
  __shared__ float tile[64][65];
  const int tid = threadIdx.x;
  const int n0 = blockIdx.x * 64;
  const int c0 = blockIdx.y * 64;
  const int col = tid & 63;
  const int row4 = tid >> 6;
#pragma unroll
  for (int i = 0; i < 16; ++i) {
    const int r = i * 4 + row4;
    tile[r][col] = src[(size_t)(c0 + r) * NTOT + n0 + col];
  }
  __syncthreads();
#pragma unroll
  for (int i = 0; i < 16; ++i) {
    const int n = i * 4 + row4;
    const float v = tile[col][n];
    const __bf16 h = (__bf16)v;
    const __bf16 l = (__bf16)(v - (float)h);
    hi[(size_t)(n0 + n) * Csz + c0 + col] = h;
    lo[(size_t)(n0 + n) * Csz + c0 + col] = l;
  }
}

// ===========================================================================
// gemm_8s: 4-slot single-tile ring, split-bf16 MFMA GEMM.
// Round-17: launch_bounds (512,2) — round-16's (512,4) forced a 64-VGPR cap
// and spilled the 128-reg accumulator (VGPR=64, FETCH 19x, MfmaUtil 7.7%).
// At ~112 VGPR (<=128) + 64KB LDS the HW naturally fits 2 blocks/CU.
// 256x256 tile, 512 thr = 8 waves (2M x 4N), BK=32, K=1024.
// LDS 64KB: A0@0(16K), B0@16K(16K), B1@32K(16K), A1@48K(16K).
// Schedule (3 phases/tile, merged p2) — ledger validated (round-16 absmax):
//   p0: vmcnt(2); bar; read A0,B0; stage A1(t);      MFMA(mh0,nh0)
//   p1: vmcnt(2); bar; read B1;    stage A0,B0(t+1); MFMA(mh0,nh1)
//   p2: vmcnt(4|0); bar; read A1;  stage B1(t+1);    MFMA(mh1,nh0)+(mh1,nh1)
// FLOP order identical to the proven kernel -> bit-identical output.
// ===========================================================================
template<int COLMAP>
__global__ __launch_bounds__(512, 2)
void gemm_8s(const __bf16* __restrict__ Ahi, const __bf16* __restrict__ Alo,
             const __bf16* __restrict__ Bhi, const __bf16* __restrict__ Blo,
             float* __restrict__ C, int ldC, int nbase,
             const float* __restrict__ bias) {
  __shared__ __align__(16) char lds[65536];

  const int tid  = threadIdx.x;
  const int wid  = tid >> 6;
  const int lane = tid & 63;
  const int wm = wid >> 2, wn = wid & 3;

  int bx = blockIdx.x, by = blockIdx.y;
  {
    const int gx = gridDim.x, gy = gridDim.y;
    const int nwg = gx * gy;
    if ((nwg & 7) == 0) {
      const int flat  = by * gx + bx;
      const int chunk = nwg >> 3;
      const int nf    = (flat & 7) * chunk + (flat >> 3);
      if (COLMAP) { bx = nf / gy; by = nf % gy; }
      else        { bx = nf % gx; by = nf / gx; }
    }
  }
  const int m0 = by * 256;
  const int n0 = bx * 256;

  const int r16 = lane & 15;
  const int kc  = lane >> 4;

  const int aq = (wid & 3) + ((wid & 4) ? 4 : 0);
  const int bq = ((wid & 3) << 1) + (wid >> 2);
  const __bf16* gAh = Ahi + (size_t)(m0 + (wid & 3) * 16 + ((wid & 4) ? 128 : 0) + r16) * Csz + kc * 8;
  const __bf16* gAl = Alo + (size_t)(m0 + (wid & 3) * 16 + ((wid & 4) ? 128 : 0) + r16) * Csz + kc * 8;
  const __bf16* gBh = Bhi + (size_t)(n0 + (wid & 3) * 64 + (wid >> 2) * 16 + r16) * Csz + kc * 8;
  const __bf16* gBl = Blo + (size_t)(n0 + (wid & 3) * 64 + (wid >> 2) * 16 + r16) * Csz + kc * 8;

  auto stA = [&](int h, int ts, char* slot) {
    const size_t o = (size_t)h * 64 * Csz + ts * 32;
    gload_lds16(gAh + o, slot + aq * 1024);
    gload_lds16(gAl + o, slot + 8192 + aq * 1024);
  };
  auto stB = [&](int h, int ts, char* slot) {
    const size_t o = (size_t)h * 32 * Csz + ts * 32;
    gload_lds16(gBh + o, slot + bq * 1024);
    gload_lds16(gBl + o, slot + 8192 + bq * 1024);
  };

  f32x4 acc[8][4];
#pragma unroll
  for (int i = 0; i < 8; ++i)
#pragma unroll
    for (int j = 0; j < 4; ++j) acc[i][j] = (f32x4)(0.f);

  // prologue: A0(0), B0(0), B1(0); A1(0) staged in p0(0)
  stA(0, 0, lds);
  stB(0, 0, lds + 16384);
  stB(1, 0, lds + 32768);

#pragma unroll 1
  for (int t = 0; t < 32; ++t) {
    bf16x8 ah[4], al[4], bh[4], bl[4];

    // ---- phase 0: read A0(t), B0(t); stage A1(t); MFMA (mh0, nh0)
    VMCNT(2);
    __builtin_amdgcn_s_barrier();
#pragma unroll
    for (int f = 0; f < 4; ++f) {
      const int off = (wm * 4 + f) * 1024 + lane * 16;
      ah[f] = *(const bf16x8*)(lds + off);
      al[f] = *(const bf16x8*)(lds + 8192 + off);
    }
#pragma unroll
    for (int j = 0; j < 2; ++j) {
      const int off = ((wn << 1) + j) * 1024 + lane * 16;
      bh[j] = *(const bf16x8*)(lds + 16384 + off);
      bl[j] = *(const bf16x8*)(lds + 16384 + 8192 + off);
    }
    stA(1, t, lds + 49152);
    __builtin_amdgcn_s_setprio(1);
#pragma unroll
    for (int f = 0; f < 4; ++f)
#pragma unroll
      for (int j = 0; j < 2; ++j) {
        f32x4 a_ = acc[f][j];
        a_ = __builtin_amdgcn_mfma_f32_16x16x32_bf16(ah[f], bh[j], a_, 0, 0, 0);
        a_ = __builtin_amdgcn_mfma_f32_16x16x32_bf16(ah[f], bl[j], a_, 0, 0, 0);
        a_ = __builtin_amdgcn_mfma_f32_16x16x32_bf16(al[f], bh[j], a_, 0, 0, 0);
        acc[f][j] = a_;
      }
    __builtin_amdgcn_s_setprio(0);

    // ---- phase 1: read B1(t); stage A0,B0(t+1); MFMA (mh0, nh1)
    VMCNT(2);
    __builtin_amdgcn_s_barrier();
#pragma unroll
    for (int j = 0; j < 2; ++j) {
      const int off = ((wn << 1) + j) * 1024 + lane * 16;
      bh[2 + j] = *(const bf16x8*)(lds + 32768 + off);
      bl[2 + j] = *(const bf16x8*)(lds + 32768 + 8192 + off);
    }
    if (t < 31) { stA(0, t + 1, lds); stB(0, t + 1, lds + 16384); }
    __builtin_amdgcn_s_setprio(1);
#pragma unroll
    for (int f = 0; f < 4; ++f)
#pragma unroll
      for (int j = 0; j < 2; ++j) {
        f32x4 a_ = acc[f][2 + j];
        a_ = __builtin_amdgcn_mfma_f32_16x16x32_bf16(ah[f], bh[2 + j], a_, 0, 0, 0);
        a_ = __builtin_amdgcn_mfma_f32_16x16x32_bf16(ah[f], bl[2 + j], a_, 0, 0, 0);
        a_ = __builtin_amdgcn_mfma_f32_16x16x32_bf16(al[f], bh[2 + j], a_, 0, 0, 0);
        acc[f][2 + j] = a_;
      }
    __builtin_amdgcn_s_setprio(0);

    // ---- phase 2 (merged): read A1(t); stage B1(t+1); MFMA (mh1, nh0+nh1)
    if (t < 31) { VMCNT(4); } else { VMCNT(0); }
    __builtin_amdgcn_s_barrier();
#pragma unroll
    for (int f = 0; f < 4; ++f) {
      const int off = (wm * 4 + f) * 1024 + lane * 16;
      ah[f] = *(const bf16x8*)(lds + 49152 + off);
      al[f] = *(const bf16x8*)(lds + 49152 + 8192 + off);
    }
    if (t < 31) stB(1, t + 1, lds + 32768);
    __builtin_amdgcn_s_setprio(1);
#pragma unroll
    for (int f = 0; f < 4; ++f)
#pragma unroll
      for (int j = 0; j < 2; ++j) {
        f32x4 a_ = acc[4 + f][j];
        a_ = __builtin_amdgcn_mfma_f32_16x16x32_bf16(ah[f], bh[j], a_, 0, 0, 0);
        a_ = __builtin_amdgcn_mfma_f32_16x16x32_bf16(ah[f], bl[j], a_, 0, 0, 0);
        a_ = __builtin_amdgcn_mfma_f32_16x16x32_bf16(al[f], bh[j], a_, 0, 0, 0);
        acc[4 + f][j] = a_;
      }
#pragma unroll
    for (int f = 0; f < 4; ++f)
#pragma unroll
      for (int j = 0; j < 2; ++j) {
        f32x4 a_ = acc[4 + f][2 + j];
        a_ = __builtin_amdgcn_mfma_f32_16x16x32_bf16(ah[f], bh[2 + j], a_, 0, 0, 0);
        a_ = __builtin_amdgcn_mfma_f32_16x16x32_bf16(ah[f], bl[2 + j], a_, 0, 0, 0);
        a_ = __builtin_amdgcn_mfma_f32_16x16x32_bf16(al[f], bh[2 + j], a_, 0, 0, 0);
        acc[4 + f][2 + j] = a_;
      }
    __builtin_amdgcn_s_setprio(0);
  }

  const int cm = m0 + wm * 128 + (lane >> 4) * 4;
  const int cn = nbase + n0 + wn * 64 + (lane & 15);
  float bb[4];
#pragma unroll
  for (int g = 0; g < 4; ++g) bb[g] = bias ? bias[cn - nbase + g * 16] : 0.f;
#pragma unroll
  for (int fm = 0; fm < 8; ++fm)
#pragma unroll
    for (int r = 0; r < 4; ++r) {
      float* cp = C + (size_t)(cm + fm * 16 + r) * ldC + cn;
#pragma unroll
      for (int g = 0; g < 4; ++g) cp[g * 16] = acc[fm][g][r] + bb[g];
    }
}

// ===========================================================================
// gemm_8s4: 4-slot ring at BM=128 (v-GEMM). LDS 48KB; launch_bounds (512,2).
// Slots: A0@0(8K), B0@8K(16K), B1@24K(16K), A1@40K(8K).
// Per-wave issues: A=1, B=2 -> vmcnt p0=2, p1=1, p2=3 (t=31: 0).
// ===========================================================================
template<int COLMAP>
__global__ __launch_bounds__(512, 2)
void gemm_8s4(const __bf16* __restrict__ Ahi, const __bf16* __restrict__ Alo,
              const __bf16* __restrict__ Bhi, const __bf16* __restrict__ Blo,
              float* __restrict__ C, int ldC, int nbase,
              const float* __restrict__ bias) {
  __shared__ __align__(16) char lds[49152];

  const int tid  = threadIdx.x;
  const int wid  = tid >> 6;
  const int lane = tid & 63;
  const int wm = wid >> 2, wn = wid & 3;

  int bx = blockIdx.x, by = blockIdx.y;
  {
    const int gx = gridDim.x, gy = gridDim.y;
    const int nwg = gx * gy;
    if ((nwg & 7) == 0) {
      const int flat  = by * gx + bx;
      const int chunk = nwg >> 3;
      const int nf    = (flat & 7) * chunk + (flat >> 3);
      if (COLMAP) { bx = nf / gy; by = nf % gy; }
      else        { bx = nf % gx; by = nf / gx; }
    }
  }
  const int m0 = by * 128;
  const int n0 = bx * 256;

  const int r16 = lane & 15;
  const int kc  = lane >> 4;

  const int cw = wid & 3;
  const __bf16* gA = ((wid & 4) ? Alo : Ahi) +
      (size_t)(m0 + (cw >> 1) * 64 + (cw & 1) * 16 + r16) * Csz + kc * 8;
  const int adst = ((wid & 4) ? 4096 : 0) + cw * 1024;
  const int bq = ((wid & 3) << 1) + (wid >> 2);
  const __bf16* gBh = Bhi + (size_t)(n0 + (wid & 3) * 64 + (wid >> 2) * 16 + r16) * Csz + kc * 8;
  const __bf16* gBl = Blo + (size_t)(n0 + (wid & 3) * 64 + (wid >> 2) * 16 + r16) * Csz + kc * 8;

  auto stA = [&](int h, int ts, char* slot) {
    gload_lds16(gA + (size_t)h * 32 * Csz + ts * 32, slot + adst);
  };
  auto stB = [&](int h, int ts, char* slot) {
    const size_t o = (size_t)h * 32 * Csz + ts * 32;
    gload_lds16(gBh + o, slot + bq * 1024);
    gload_lds16(gBl + o, slot + 8192 + bq * 1024);
  };

  f32x4 acc[4][4];
#pragma unroll
  for (int i = 0; i < 4; ++i)
#pragma unroll
    for (int j = 0; j < 4; ++j) acc[i][j] = (f32x4)(0.f);

  stA(0, 0, lds);
  stB(0, 0, lds + 8192);
  stB(1, 0, lds + 24576);

#pragma unroll 1
  for (int t = 0; t < 32; ++t) {
    bf16x8 ah[2], al[2], bh[4], bl[4];

    // ---- phase 0: read A0, B0; stage A1(t); MFMA (mh0, nh0)
    VMCNT(2);
    __builtin_amdgcn_s_barrier();
#pragma unroll
    for (int f = 0; f < 2; ++f) {
      const int off = (wm * 2 + f) * 1024 + lane * 16;
      ah[f] = *(const bf16x8*)(lds + off);
      al[f] = *(const bf16x8*)(lds + 4096 + off);
    }
#pragma unroll
    for (int j = 0; j < 2; ++j) {
      const int off = ((wn << 1) + j) * 1024 + lane * 16;
      bh[j] = *(const bf16x8*)(lds + 8192 + off);
      bl[j] = *(const bf16x8*)(lds + 8192 + 8192 + off);
    }
    stA(1, t, lds + 40960);
    __builtin_amdgcn_s_setprio(1);
#pragma unroll
    for (int f = 0; f < 2; ++f)
#pragma unroll
      for (int j = 0; j < 2; ++j) {
        f32x4 a_ = acc[f][j];
        a_ = __builtin_amdgcn_mfma_f32_16x16x32_bf16(ah[f], bh[j], a_, 0, 0, 0);
        a_ = __builtin_amdgcn_mfma_f32_16x16x32_bf16(ah[f], bl[j], a_, 0, 0, 0);
        a_ = __builtin_amdgcn_mfma_f32_16x16x32_bf16(al[f], bh[j], a_, 0, 0, 0);
        acc[f][j] = a_;
      }
    __builtin_amdgcn_s_setprio(0);

    // ---- phase 1: read B1; stage A0,B0(t+1); MFMA (mh0, nh1)
    VMCNT(1);
    __builtin_amdgcn_s_barrier();
#pragma unroll
    for (int j = 0; j < 2; ++j) {
      const int off = ((wn << 1) + j) * 1024 + lane * 16;
      bh[2 + j] = *(const bf16x8*)(lds + 24576 + off);
      bl[2 + j] = *(const bf16x8*)(lds + 24576 + 8192 + off);
    }
    if (t < 31) { stA(0, t + 1, lds); stB(0, t + 1, lds + 8192); }
    __builtin_amdgcn_s_setprio(1);
#pragma unroll
    for (int f = 0; f < 2; ++f)
#pragma unroll
      for (int j = 0; j < 2; ++j) {
        f32x4 a_ = acc[f][2 + j];
        a_ = __builtin_amdgcn_mfma_f32_16x16x32_bf16(ah[f], bh[2 + j], a_, 0, 0, 0);
        a_ = __builtin_amdgcn_mfma_f32_16x16x32_bf16(ah[f], bl[2 + j], a_, 0, 0, 0);
        a_ = __builtin_amdgcn_mfma_f32_16x16x32_bf16(al[f], bh[2 + j], a_, 0, 0, 0);
        acc[f][2 + j] = a_;
      }
    __builtin_amdgcn_s_setprio(0);

    // ---- phase 2 (merged): read A1; stage B1(t+1); MFMA (mh1, nh0+nh1)
    if (t < 31) { VMCNT(3); } else { VMCNT(0); }
    __builtin_amdgcn_s_barrier();
#pragma unroll
    for (int f = 0; f < 2; ++f) {
      const int off = (wm * 2 + f) * 1024 + lane * 16;
      ah[f] = *(const bf16x8*)(lds + 40960 + off);
      al[f] = *(const bf16x8*)(lds + 40960 + 4096 + off);
    }
    if (t < 31) stB(1, t + 1, lds + 24576);
    __builtin_amdgcn_s_setprio(1);
#pragma unroll
    for (int f = 0; f < 2; ++f)
#pragma unroll
      for (int j = 0; j < 2; ++j) {
        f32x4 a_ = acc[2 + f][j];
        a_ = __builtin_amdgcn_mfma_f32_16x16x32_bf16(ah[f], bh[j], a_, 0, 0, 0);
        a_ = __builtin_amdgcn_mfma_f32_16x16x32_bf16(ah[f], bl[j], a_, 0, 0, 0);
        a_ = __builtin_amdgcn_mfma_f32_16x16x32_bf16(al[f], bh[j], a_, 0, 0, 0);
        acc[2 + f][j] = a_;
      }
#pragma unroll
    for (int f = 0; f < 2; ++f)
#pragma unroll
      for (int j = 0; j < 2; ++j) {
        f32x4 a_ = acc[2 + f][2 + j];
        a_ = __builtin_amdgcn_mfma_f32_16x16x32_bf16(ah[f], bh[2 + j], a_, 0, 0, 0);
        a_ = __builtin_amdgcn_mfma_f32_16x16x32_bf16(ah[f], bl[2 + j], a_, 0, 0, 0);
        a_ = __builtin_amdgcn_mfma_f32_16x16x32_bf16(al[f], bh[2 + j], a_, 0, 0, 0);
        acc[2 + f][2 + j] = a_;
      }
    __builtin_amdgcn_s_setprio(0);
  }

  const int cm = m0 + wm * 64 + (lane >> 4) * 4;
  const int cn = nbase + n0 + wn * 64 + (lane & 15);
  float bb[4];
#pragma unroll
  for (int g = 0; g < 4; ++g) bb[g] = bias ? bias[cn - nbase + g * 16] : 0.f;
#pragma unroll
  for (int fm = 0; fm < 4; ++fm)
#pragma unroll
    for (int r = 0; r < 4; ++r) {
      float* cp = C + (size_t)(cm + fm * 16 + r) * ldC + cn;
#pragma unroll
      for (int g = 0; g < 4; ++g) cp[g * 16] = acc[fm][g][r] + bb[g];
    }
}

// ===========================================================================
// Radix-4 Stockham FFT, 4096 = 4^6, 6 stages, LDS twiddle table.
// PAIRED variant (round-13 proven): 512 threads, thread u handles
// butterflies {2u, 2u+1}; float4 LDS reads/writes; shared twiddles per pair
// for stages >=1. Bit-identical to the unpaired version.
// ===========================================================================
__device__ __forceinline__ void build_twiddle512(float2* tw, int tid) {
  const float k = 6.28318530717958647692f / 4096.0f;
#pragma unroll
  for (int i = 0; i < 2; ++i) {
    const int e = tid + i * 512;
    float sn, cs;
    __sincosf(k * (float)e, &sn, &cs);
    tw[e] = make_float2(cs, sn);
  }
}

__device__ __forceinline__ float2 cmul(float2 a, float2 b) {
  return make_float2(a.x * b.x - a.y * b.y, a.x * b.y + a.y * b.x);
}

__device__ __forceinline__ void fft4096_r4p(float2* X, float2* Y,
                                            const float2* __restrict__ tw,
                                            int tid, float sign) {
  float2* src = X;
  float2* dst = Y;
#pragma unroll 1
  for (int stage = 0; stage < 6; ++stage) {
    const int s = 1 << (2 * stage);
    __syncthreads();
    const int i0 = tid << 1;                    // 0,2,...,1022
    float4 A0 = *(const float4*)(src + i0);
    float4 A1 = *(const float4*)(src + i0 + 1024);
    float4 A2 = *(const float4*)(src + i0 + 2048);
    float4 A3 = *(const float4*)(src + i0 + 3072);
    float2 y[2][4];
#pragma unroll
    for (int e = 0; e < 2; ++e) {
      const float2 a0 = e ? make_float2(A0.z, A0.w) : make_float2(A0.x, A0.y);
      const float2 a1 = e ? make_float2(A1.z, A1.w) : make_float2(A1.x, A1.y);
      const float2 a2 = e ? make_float2(A2.z, A2.w) : make_float2(A2.x, A2.y);
      const float2 a3 = e ? make_float2(A3.z, A3.w) : make_float2(A3.x, A3.y);
      float2 b0 = make_float2(a0.x + a2.x, a0.y + a2.y);
      float2 b1 = make_float2(a0.x - a2.x, a0.y - a2.y);
      float2 b2 = make_float2(a1.x + a3.x, a1.y + a3.y);
      float2 b3 = make_float2(a1.x - a3.x, a1.y - a3.y);
      y[e][0] = make_float2(b0.x + b2.x, b0.y + b2.y);
      y[e][2] = make_float2(b0.x - b2.x, b0.y - b2.y);
      y[e][1] = make_float2(b1.x - sign * b3.y, b1.y + sign * b3.x);
      y[e][3] = make_float2(b1.x + sign * b3.y, b1.y - sign * b3.x);
    }
    if (stage == 0) {
#pragma unroll
      for (int e = 0; e < 2; ++e) {
        const int idx = i0 + e;
        float2 w1 = tw[idx];
        w1.y *= sign;
        float2 w2 = make_float2(w1.x * w1.x - w1.y * w1.y, 2.f * w1.x * w1.y);
        float2 w3 = cmul(w1, w2);
        float2 t1 = cmul(w1, y[e][1]);
        float2 t2 = cmul(w2, y[e][2]);
        float2 t3 = cmul(w3, y[e][3]);
        const int o = idx << 2;
        *(float4*)(dst + o)     = make_float4(y[e][0].x, y[e][0].y, t1.x, t1.y);
        *(float4*)(dst + o + 2) = make_float4(t2.x, t2.y, t3.x, t3.y);
      }
    } else {
      const int sp = i0 & ~(s - 1);
      float2 w1 = tw[sp];
      w1.y *= sign;
      float2 w2 = make_float2(w1.x * w1.x - w1.y * w1.y, 2.f * w1.x * w1.y);
      float2 w3 = cmul(w1, w2);
      const int o = i0 + 3 * sp;
      *(float4*)(dst + o) = make_float4(y[0][0].x, y[0][0].y, y[1][0].x, y[1][0].y);
      float2 p0 = cmul(w1, y[0][1]);
      float2 p1 = cmul(w1, y[1][1]);
      *(float4*)(dst + o + s) = make_float4(p0.x, p0.y, p1.x, p1.y);
      p0 = cmul(w2, y[0][2]);
      p1 = cmul(w2, y[1][2]);
      *(float4*)(dst + o + 2 * s) = make_float4(p0.x, p0.y, p1.x, p1.y);
      p0 = cmul(w3, y[0][3]);
      p1 = cmul(w3, y[1][3]);
      *(float4*)(dst + o + 3 * s) = make_float4(p0.x, p0.y, p1.x, p1.y);
    }
    float2* t = src; src = dst; dst = t;
  }
  __syncthreads();
}

// ---------------------------------------------------------------------------
// qk_cross (512 thr): z = q + i*k, FFT, Re(conj(Q)K) via packed extraction.
// ---------------------------------------------------------------------------
__global__ __launch_bounds__(512)
void qk_cross_kernel(const float* __restrict__ qkT, float* __restrict__ attn_raw,
                     int bhbase) {
  __shared__ float2 bufA[4096];
  __shared__ float2 bufB[4096];
  __shared__ float2 twid[1024];
  const int tid = threadIdx.x;
  const int blk = blockIdx.x;
  const int d = blk & 63;
  const int bh = bhbase + (blk >> 6);
  const int h = bh & 15;
  const int b = bh >> 4;

  build_twiddle512(twid, tid);

  const float4* qrow = (const float4*)(qkT + (size_t)(h * DHn + d) * NTOT + b * Tsz);
  const float4* krow = (const float4*)(qkT + (size_t)(Csz + h * DHn + d) * NTOT + b * Tsz);
#pragma unroll
  for (int i = 0; i < 2; ++i) {
    const int t4 = tid + (i << 9);           // < 1024
    float4 qv = qrow[t4];
    float4 kv = krow[t4];
    bufA[t4 * 4 + 0] = make_float2(qv.x, kv.x);
    bufA[t4 * 4 + 1] = make_float2(qv.y, kv.y);
    bufA[t4 * 4 + 2] = make_float2(qv.z, kv.z);
    bufA[t4 * 4 + 3] = make_float2(qv.w, kv.w);
  }

  fft4096_r4p(bufA, bufB, twid, tid, -1.0f);

  float* outp = attn_raw + (size_t)bh * Fn;
  for (int f = tid; f < Fn; f += 512) {
    float2 zf = bufA[f];
    float2 zn = bufA[(4096 - f) & 4095];
    float ar = zf.x + zn.x;
    float ai = zf.y - zn.y;
    float br = zf.x - zn.x;
    float bi = zf.y + zn.y;
    float val = 0.03125f * (ar * bi - ai * br);
    atomicAdd(&outp[f], val);
  }
}

// ---------------------------------------------------------------------------
__global__ __launch_bounds__(256)
void softmax_kernel(const float* __restrict__ raw, float* __restrict__ attn) {
  __shared__ float red[256];
  const int tid = threadIdx.x;
  const float* in = raw + (size_t)blockIdx.x * Fn;
  float* outp = attn + (size_t)blockIdx.x * Fn;

  float lmax = -3.4e38f;
  for (int f = tid; f < Fn; f += 256) lmax = fmaxf(lmax, in[f]);
  red[tid] = lmax;
  __syncthreads();
  for (int off = 128; off > 0; off >>= 1) {
    if (tid < off) red[tid] = fmaxf(red[tid], red[tid + off]);
    __syncthreads();
  }
  const float mx = red[0];
  __syncthreads();

  float lsum = 0.f;
  for (int f = tid; f < Fn; f += 256) lsum += __expf(in[f] - mx);
  red[tid] = lsum;
  __syncthreads();
  for (int off = 128; off > 0; off >>= 1) {
    if (tid < off) red[tid] += red[tid + off];
    __syncthreads();
  }
  const float inv = 1.0f / red[0];
  for (int f = tid; f < Fn; f += 256) outp[f] = __expf(in[f] - mx) * inv;
}

// ---------------------------------------------------------------------------
// v_filter (512 thr): z = v[d0]+i*v[d1]; FFT; real symmetric filter; IFFT.
// ---------------------------------------------------------------------------
__global__ __launch_bounds__(512)
void v_filter_kernel(const float* __restrict__ vT, float* __restrict__ vbarT,
                     const float* __restrict__ attn) {
  __shared__ float2 bufA[4096];
  __shared__ float2 bufB[4096];
  __shared__ float2 twid[1024];
  const int tid = threadIdx.x;
  const int blk = blockIdx.x;
  const int jp = blk & 31;
  const int bh = blk >> 5;
  const int h = bh & 15;
  const int b = bh >> 4;
  const int d0 = jp * 2;

  build_twiddle512(twid, tid);

  const float4* v0 = (const float4*)(vT + (size_t)(h * DHn + d0) * NTOT + b * Tsz);
  const float4* v1 = (const float4*)(vT + (size_t)(h * DHn + d0 + 1) * NTOT + b * Tsz);
#pragma unroll
  for (int i = 0; i < 2; ++i) {
    const int t4 = tid + (i << 9);
    float4 av = v0[t4];
    float4 bv = v1[t4];
    bufA[t4 * 4 + 0] = make_float2(av.x, bv.x);
    bufA[t4 * 4 + 1] = make_float2(av.y, bv.y);
    bufA[t4 * 4 + 2] = make_float2(av.z, bv.z);
    bufA[t4 * 4 + 3] = make_float2(av.w, bv.w);
  }

  fft4096_r4p(bufA, bufB, twid, tid, -1.0f);

  const float* a = attn + (size_t)bh * Fn;
  for (int f = tid; f < 4096; f += 512) {
    int fm = (f <= 2048) ? f : (4096 - f);
    float s = a[fm];
    float2 z = bufA[f];
    bufA[f] = make_float2(z.x * s, z.y * s);
  }

  fft4096_r4p(bufA, bufB, twid, tid, +1.0f);

  float* y0 = vbarT + (size_t)(h * DHn + d0) * NTOT + b * Tsz;
  float* y1 = y0 + NTOT;
  const float inv = 1.0f / 4096.0f;
  for (int t = tid; t < 4096; t += 512) {
    float2 z = bufA[t];
    y0[t] = z.x * inv;
    y1[t] = z.y * inv;
  }
}

__global__ void zero_kernel(float* __restrict__ p, int n) {
  int i = blockIdx.x * blockDim.x + threadIdx.x;
  if (i < n) p[i] = 0.f;
}

// ---------------------------------------------------------------------------
// Workspace layout (peak 185,598,464 B <= 202.9 MB proven by round 1):
//   [0,           67108864)   q rows of qkT; later vT; finally VThi/VTlo.
//   [67108864,   134217728)   k rows of qkT; later vbarT.
//   [134217728,  134742272)   attn_raw [64][2049] f32
//   [134742272,  135266816)   attn     [64][2049] f32
//   [135266816,  141558272)   Whi [3072][1024] bf16
//   [141558272,  147849728)   Wlo
//   [147849728,  164626944)   Xhi half [8192][1024] bf16 (2 halves, reused)
//   [164626944,  181404160)   Xlo half
//   [181404160,  183501312)   Wouthi [1024][1024] bf16
//   [183501312,  185598464)   Woutlo
// ---------------------------------------------------------------------------
extern "C" void kernel_launch(void* const* d_in, const int* in_sizes, int n_in,
                              void* d_out, int out_size, void* d_ws, size_t ws_size,
                              hipStream_t stream) {
  const float* x    = (const float*)d_in[0];   // [4,4096,1024]
  const float* Wqkv = (const float*)d_in[1];   // [3072,1024]
  const float* Wout = (const float*)d_in[2];   // [1024,1024]
  const float* bout = (const float*)d_in[3];   // [1024]
  float* out = (float*)d_out;                  // [16384,1024]

  char* ws = (char*)d_ws;
  float* qkT      = (float*)ws;
  float* vT       = (float*)ws;
  __bf16* VThi    = (__bf16*)ws;
  __bf16* VTlo    = (__bf16*)(ws + 33554432ull);
  float* vbarT    = (float*)(ws + 67108864ull);
  float* attn_raw = (float*)(ws + 134217728ull);
  float* attn     = (float*)(ws + 134742272ull);
  __bf16* Whi     = (__bf16*)(ws + 135266816ull);
  __bf16* Wlo     = (__bf16*)(ws + 141558272ull);
  __bf16* Xhi     = (__bf16*)(ws + 147849728ull);
  __bf16* Xlo     = (__bf16*)(ws + 164626944ull);
  __bf16* Wouthi  = (__bf16*)(ws + 181404160ull);
  __bf16* Woutlo  = (__bf16*)(ws + 183501312ull);

  const int nraw = BHn * Fn;
  zero_kernel<<<(nraw + 255) / 256, 256, 0, stream>>>(attn_raw, nraw);

  // Weights -> hi/lo
  cvt_hilo_kernel<<<3072, 256, 0, stream>>>((const float4*)Wqkv,
                                            (bf16x4*)Whi, (bf16x4*)Wlo, 786432);
  cvt_hilo_kernel<<<1024, 256, 0, stream>>>((const float4*)Wout,
                                            (bf16x4*)Wouthi, (bf16x4*)Woutlo, 262144);

  // Per 2-batch half: convert X, q/k GEMM (4-slot ring), qk cross, v GEMM
  for (int half = 0; half < 2; ++half) {
    cvt_hilo_kernel<<<8192, 256, 0, stream>>>(
        (const float4*)(x + (size_t)half * HALFN * Csz),
        (bf16x4*)Xhi, (bf16x4*)Xlo, 2097152);
    gemm_8s<1><<<dim3(32, 8), 512, 0, stream>>>(Whi, Wlo, Xhi, Xlo,
                                                qkT, NTOT, half * HALFN, nullptr);
    qk_cross_kernel<<<2048, 512, 0, stream>>>(qkT, attn_raw, half * 32);
    gemm_8s4<1><<<dim3(32, 8), 512, 0, stream>>>(Whi + 2048 * Csz, Wlo + 2048 * Csz,
                                                 Xhi, Xlo, vT, NTOT, half * HALFN,
                                                 nullptr);
  }

  softmax_kernel<<<BHn, 256, 0, stream>>>(attn_raw, attn);

  v_filter_kernel<<<2048, 512, 0, stream>>>(vT, vbarT, attn);

  transpose_cvt_kernel<<<dim3(NTOT / 64, Csz / 64), 256, 0, stream>>>(vbarT, VThi, VTlo);

  gemm_8s<0><<<dim3(4, 64), 512, 0, stream>>>(VThi, VTlo, Wouthi, Woutlo,
                                              out, Csz, 0, bout);
}